// Round 1
// baseline (42296.405 us; speedup 1.0000x reference)
//
#include <hip/hip_runtime.h>

typedef unsigned int uint;
typedef unsigned long long u64;
typedef __attribute__((ext_vector_type(4))) float f32x4;
typedef __attribute__((ext_vector_type(8))) short s16x8;   // 8 bf16 in 4 VGPRs

union U4 { uint u[4]; s16x8 v; uint4 q; };

#define TT 4096
#define HC2 512

// ---------- helpers ----------
__device__ __forceinline__ uint bf16_rne(float f) {
  uint x = __float_as_uint(f);
  x += 0x7fffu + ((x >> 16) & 1u);
  return x >> 16;
}
// split f into hi(bf16, low 16 bits) + lo(bf16 of remainder, high 16 bits)
__device__ __forceinline__ uint pack_split(float f) {
  uint hi = bf16_rne(f);
  float fh = __uint_as_float(hi << 16);
  uint lo = bf16_rne(f - fh);
  return hi | (lo << 16);
}
__device__ __forceinline__ float fast_tanh(float y) {
  // tanh(y) = 1 - 2/(exp2(y*2*log2e)+1); exp2 overflow/underflow give correct +-1
  float e = __builtin_amdgcn_exp2f(y * 2.885390081777927f);
  return 1.0f - 2.0f * __builtin_amdgcn_rcpf(e + 1.0f);
}

// ---------- pack weights: M[k][j] stored transposed+split as MT[j][k] (uint32) ----------
// M (512x512) built from complex pair (r,i):  k<256,j<256:+r | k<256,j>=256:+i
//                                             k>=256,j<256:-i | k>=256,j>=256:+r
__global__ void pack_weights_kernel(const float* __restrict__ wr, const float* __restrict__ wi,
                                    const float* __restrict__ wbr, const float* __restrict__ wbi,
                                    const float* __restrict__ ur, const float* __restrict__ ui,
                                    const float* __restrict__ ubr, const float* __restrict__ ubi,
                                    uint* __restrict__ MwT, uint* __restrict__ MuT,
                                    float* __restrict__ bias) {
  const int id = blockIdx.x * 256 + threadIdx.x;   // 0..262143
  const int j = id >> 9, k = id & 511;
  const int jj = j & 255, kk = k & 255;
  float mw, mu;
  if (k < 256) {
    if (j < 256) { mw =  wr[kk * 256 + jj]; mu =  ur[kk * 256 + jj]; }
    else         { mw =  wi[kk * 256 + jj]; mu =  ui[kk * 256 + jj]; }
  } else {
    if (j < 256) { mw = -wi[kk * 256 + jj]; mu = -ui[kk * 256 + jj]; }
    else         { mw =  wr[kk * 256 + jj]; mu =  ur[kk * 256 + jj]; }
  }
  MwT[id] = pack_split(mw);                        // id == j*512 + k  -> [j][k]
  MuT[id] = pack_split(mu);
  if (id < 512)                                    // bias = wb + ub (recurrent bias folded in)
    bias[id] = (id < 256) ? (wbr[id] + ubr[id]) : (wbi[id - 256] + ubi[id - 256]);
}

// ---------- pack x (fp32 -> split uint32) ----------
__global__ void pack_x_kernel(const float* __restrict__ x, uint* __restrict__ xp) {
  const u64 i = ((u64)blockIdx.x * 256 + threadIdx.x) * 4;
  float4 v = *(const float4*)(x + i);
  uint4 o;
  o.x = pack_split(v.x); o.y = pack_split(v.y);
  o.z = pack_split(v.z); o.w = pack_split(v.w);
  *(uint4*)(xp + i) = o;
}

// ---------- split-bf16 MFMA GEMM:  C[M=32768][512] = A[M][512] * B[512][512] + bias ----------
// A packed split uint32 [row][k]; BT packed split uint32 [j][k] (i.e. B transposed)
__global__ __launch_bounds__(256, 2)
void gemm_split_kernel(const uint* __restrict__ A, const uint* __restrict__ BT,
                       const float* __restrict__ bias, float* __restrict__ C) {
  __shared__ __align__(16) uint a_s[128][36];   // pad 4 -> stride%32==4: minimal bank cycles
  __shared__ __align__(16) uint b_s[128][36];
  const int tid = threadIdx.x;
  const int wv = tid >> 6, lane = tid & 63;
  const int q = lane >> 4, cl = lane & 15;
  const int row0 = (int)blockIdx.x * 128, col0 = (int)blockIdx.y * 128;
  const int wro = (wv >> 1) * 64, wco = (wv & 1) * 64;   // wave quadrant
  const int sr = tid >> 1, sc = (tid & 1) * 16;          // staging coords

  f32x4 acc[4][4];
#pragma unroll
  for (int a = 0; a < 4; ++a)
#pragma unroll
    for (int b = 0; b < 4; ++b) acc[a][b] = (f32x4){0.f, 0.f, 0.f, 0.f};

  const uint* ga = A + (u64)(row0 + sr) * 512 + sc;
  const uint* gb = BT + (u64)(col0 + sr) * 512 + sc;

  for (int kb = 0; kb < 16; ++kb) {
    uint4 va0 = *(const uint4*)(ga + 0), va1 = *(const uint4*)(ga + 4);
    uint4 va2 = *(const uint4*)(ga + 8), va3 = *(const uint4*)(ga + 12);
    uint4 vb0 = *(const uint4*)(gb + 0), vb1 = *(const uint4*)(gb + 4);
    uint4 vb2 = *(const uint4*)(gb + 8), vb3 = *(const uint4*)(gb + 12);
    ga += 32; gb += 32;
    __syncthreads();                       // previous iteration's reads done
    *(uint4*)&a_s[sr][sc + 0] = va0;  *(uint4*)&a_s[sr][sc + 4] = va1;
    *(uint4*)&a_s[sr][sc + 8] = va2;  *(uint4*)&a_s[sr][sc + 12] = va3;
    *(uint4*)&b_s[sr][sc + 0] = vb0;  *(uint4*)&b_s[sr][sc + 4] = vb1;
    *(uint4*)&b_s[sr][sc + 8] = vb2;  *(uint4*)&b_s[sr][sc + 12] = vb3;
    __syncthreads();

    s16x8 ah[4], al[4];
#pragma unroll
    for (int rt = 0; rt < 4; ++rt) {       // A frags: row=lane&15, k=q*8+e
      const uint* p = &a_s[wro + rt * 16 + cl][q * 8];
      uint4 p0 = *(const uint4*)(p), p1 = *(const uint4*)(p + 4);
      U4 th, tl;
      th.u[0] = (p0.x & 0xffffu) | (p0.y << 16);
      th.u[1] = (p0.z & 0xffffu) | (p0.w << 16);
      th.u[2] = (p1.x & 0xffffu) | (p1.y << 16);
      th.u[3] = (p1.z & 0xffffu) | (p1.w << 16);
      tl.u[0] = (p0.x >> 16) | (p0.y & 0xffff0000u);
      tl.u[1] = (p0.z >> 16) | (p0.w & 0xffff0000u);
      tl.u[2] = (p1.x >> 16) | (p1.y & 0xffff0000u);
      tl.u[3] = (p1.z >> 16) | (p1.w & 0xffff0000u);
      ah[rt] = th.v; al[rt] = tl.v;
    }
#pragma unroll
    for (int ct = 0; ct < 4; ++ct) {       // B frags: col=lane&15, k=q*8+e
      const uint* p = &b_s[wco + ct * 16 + cl][q * 8];
      uint4 p0 = *(const uint4*)(p), p1 = *(const uint4*)(p + 4);
      U4 th, tl;
      th.u[0] = (p0.x & 0xffffu) | (p0.y << 16);
      th.u[1] = (p0.z & 0xffffu) | (p0.w << 16);
      th.u[2] = (p1.x & 0xffffu) | (p1.y << 16);
      th.u[3] = (p1.z & 0xffffu) | (p1.w << 16);
      tl.u[0] = (p0.x >> 16) | (p0.y & 0xffff0000u);
      tl.u[1] = (p0.z >> 16) | (p0.w & 0xffff0000u);
      tl.u[2] = (p1.x >> 16) | (p1.y & 0xffff0000u);
      tl.u[3] = (p1.z >> 16) | (p1.w & 0xffff0000u);
#pragma unroll
      for (int rt = 0; rt < 4; ++rt) {
        acc[rt][ct] = __builtin_amdgcn_mfma_f32_16x16x32_bf16(ah[rt], th.v, acc[rt][ct], 0, 0, 0);
        acc[rt][ct] = __builtin_amdgcn_mfma_f32_16x16x32_bf16(al[rt], th.v, acc[rt][ct], 0, 0, 0);
        acc[rt][ct] = __builtin_amdgcn_mfma_f32_16x16x32_bf16(ah[rt], tl.v, acc[rt][ct], 0, 0, 0);
      }
    }
  }
  // epilogue: C/D layout col=lane&15, row=q*4+reg
#pragma unroll
  for (int ct = 0; ct < 4; ++ct) {
    const int col = col0 + wco + ct * 16 + cl;
    const float bv = bias[col];
#pragma unroll
    for (int rt = 0; rt < 4; ++rt) {
      const int rbase = row0 + wro + rt * 16 + q * 4;
#pragma unroll
      for (int r2 = 0; r2 < 4; ++r2)
        C[(u64)(rbase + r2) * 512 + col] = acc[rt][ct][r2] + bv;
    }
  }
}

// ---------- persistent scan: 8 blocks, block w owns output cols [64w,64w+64) ----------
// h exchange: xbuf[2 parities][8][512] packed uint32, monotone counter sync.
__global__ __launch_bounds__(256, 1)
void scan_kernel(const uint* __restrict__ MuT, const float* __restrict__ wxb,
                 float* __restrict__ hout, uint* __restrict__ hpk,
                 uint* __restrict__ xbuf, u64* __restrict__ cnt) {
  __shared__ __align__(16) unsigned short xah[16][520];  // hi plane, rows 8..15 stay zero
  __shared__ __align__(16) unsigned short xal[16][520];  // lo plane
  const int tid = threadIdx.x;
  const int wv = tid >> 6, lane = tid & 63;
  const int q = lane >> 4, cl = lane & 15;
  const int j = (int)blockIdx.x * 64 + wv * 16 + cl;     // this lane's output column

  for (int idx = tid; idx < 16 * 520; idx += 256) {
    ((unsigned short*)xah)[idx] = 0;
    ((unsigned short*)xal)[idx] = 0;
  }

  // recurrent weights -> registers (split bf16 frags for B operand: col=lane&15, k=q*8+e)
  uint bh[64], bl[64];
  {
    const uint* wrow = MuT + (u64)j * 512;
#pragma unroll
    for (int ks = 0; ks < 16; ++ks) {
      const int k0 = ks * 32 + q * 8;
      uint4 p0 = *(const uint4*)(wrow + k0);
      uint4 p1 = *(const uint4*)(wrow + k0 + 4);
      bh[ks * 4 + 0] = (p0.x & 0xffffu) | (p0.y << 16);
      bh[ks * 4 + 1] = (p0.z & 0xffffu) | (p0.w << 16);
      bh[ks * 4 + 2] = (p1.x & 0xffffu) | (p1.y << 16);
      bh[ks * 4 + 3] = (p1.z & 0xffffu) | (p1.w << 16);
      bl[ks * 4 + 0] = (p0.x >> 16) | (p0.y & 0xffff0000u);
      bl[ks * 4 + 1] = (p0.z >> 16) | (p0.w & 0xffff0000u);
      bl[ks * 4 + 2] = (p1.x >> 16) | (p1.y & 0xffff0000u);
      bl[ks * 4 + 3] = (p1.z >> 16) | (p1.w & 0xffff0000u);
    }
  }
  __syncthreads();

  const int srow = tid >> 5;            // staging: 32 threads per batch row
  const int scol = (tid & 31) * 16;

#pragma unroll 1
  for (int t = 0; t < TT; ++t) {
    f32x4 acc0 = {0.f, 0.f, 0.f, 0.f}, acc1 = acc0, acc2 = acc0;
    if (t > 0) {
      const u64 target = (u64)8 * (u64)t;
      if (lane == 0) {
        while (__hip_atomic_load(cnt, __ATOMIC_ACQUIRE, __HIP_MEMORY_SCOPE_AGENT) < target)
          __builtin_amdgcn_s_sleep(1);
      }
      __syncthreads();
      { // stage h(t) from xbuf[t&1] into LDS hi/lo planes
        const uint* src = xbuf + (u64)(t & 1) * (8 * 512) + srow * 512 + scol;
        uint pcs[16];
#pragma unroll
        for (int e = 0; e < 8; ++e) {
          u64 v = __hip_atomic_load((const u64*)src + e, __ATOMIC_RELAXED, __HIP_MEMORY_SCOPE_AGENT);
          pcs[2 * e] = (uint)v;
          pcs[2 * e + 1] = (uint)(v >> 32);
        }
        U4 h0, h1, l0, l1;
#pragma unroll
        for (int e = 0; e < 4; ++e) {
          h0.u[e] = (pcs[2 * e] & 0xffffu) | (pcs[2 * e + 1] << 16);
          l0.u[e] = (pcs[2 * e] >> 16) | (pcs[2 * e + 1] & 0xffff0000u);
          h1.u[e] = (pcs[8 + 2 * e] & 0xffffu) | (pcs[8 + 2 * e + 1] << 16);
          l1.u[e] = (pcs[8 + 2 * e] >> 16) | (pcs[8 + 2 * e + 1] & 0xffff0000u);
        }
        *(uint4*)&xah[srow][scol] = h0.q;  *(uint4*)&xah[srow][scol + 8] = h1.q;
        *(uint4*)&xal[srow][scol] = l0.q;  *(uint4*)&xal[srow][scol + 8] = l1.q;
      }
      __syncthreads();
      // U*h : A frag row=lane&15 (batch), k=q*8+e
#pragma unroll
      for (int ks = 0; ks < 16; ++ks) {
        const int k0 = ks * 32 + q * 8;
        s16x8 ah = *(const s16x8*)&xah[cl][k0];
        s16x8 al = *(const s16x8*)&xal[cl][k0];
        U4 tb, tc;
        tb.u[0] = bh[ks * 4 + 0]; tb.u[1] = bh[ks * 4 + 1];
        tb.u[2] = bh[ks * 4 + 2]; tb.u[3] = bh[ks * 4 + 3];
        tc.u[0] = bl[ks * 4 + 0]; tc.u[1] = bl[ks * 4 + 1];
        tc.u[2] = bl[ks * 4 + 2]; tc.u[3] = bl[ks * 4 + 3];
        acc0 = __builtin_amdgcn_mfma_f32_16x16x32_bf16(ah, tb.v, acc0, 0, 0, 0);
        acc1 = __builtin_amdgcn_mfma_f32_16x16x32_bf16(al, tb.v, acc1, 0, 0, 0);
        acc2 = __builtin_amdgcn_mfma_f32_16x16x32_bf16(ah, tc.v, acc2, 0, 0, 0);
      }
    }
    // epilogue: D row=q*4+r (batch, valid q<2), col=cl
    if (q < 2) {
#pragma unroll
      for (int r = 0; r < 4; ++r) {
        const int b = q * 4 + r;
        const u64 off = ((u64)b * TT + t) * HC2 + j;
        float y = acc0[r] + acc1[r] + acc2[r] + wxb[off];
        float h = fast_tanh(y);
        if (hout) hout[off] = h;
        const uint pk = pack_split(h);
        if (hpk) hpk[off] = pk;
        __hip_atomic_store(xbuf + (u64)((t + 1) & 1) * (8 * 512) + b * 512 + j, pk,
                           __ATOMIC_RELAXED, __HIP_MEMORY_SCOPE_AGENT);
      }
    }
    if (t < TT - 1) {
      __syncthreads();   // compiler drains vmcnt before s_barrier -> stores visible
      if (tid == 0)
        __hip_atomic_fetch_add(cnt, (u64)1, __ATOMIC_RELEASE, __HIP_MEMORY_SCOPE_AGENT);
    }
  }
}

// ---------- host ----------
extern "C" void kernel_launch(void* const* d_in, const int* in_sizes, int n_in,
                              void* d_out, int out_size, void* d_ws, size_t ws_size,
                              hipStream_t stream) {
  const float* x = (const float*)d_in[0];
  const float* L0[8]; const float* L1[8];
  for (int i = 0; i < 8; ++i) { L0[i] = (const float*)d_in[1 + i]; L1[i] = (const float*)d_in[9 + i]; }

  char* ws = (char*)d_ws;
  const size_t MB = 1024 * 1024;
  uint* MwT0 = (uint*)(ws + 0 * MB);
  uint* MuT0 = (uint*)(ws + 1 * MB);
  uint* MwT1 = (uint*)(ws + 2 * MB);
  uint* MuT1 = (uint*)(ws + 3 * MB);
  float* bias0 = (float*)(ws + 4 * MB);
  float* bias1 = (float*)(ws + 4 * MB + 8192);
  u64* cnts = (u64*)(ws + 4 * MB + 16384);
  uint* xb0 = (uint*)(ws + 4 * MB + 32768);
  uint* xb1 = (uint*)(ws + 4 * MB + 65536);
  uint* Apk = (uint*)(ws + 8 * MB);      // 64 MB: packed x, then packed h0
  float* wx = (float*)(ws + 72 * MB);    // 64 MB: projection output (both layers)

  hipMemsetAsync(cnts, 0, 256, stream);
  pack_weights_kernel<<<1024, 256, 0, stream>>>(L0[0], L0[1], L0[2], L0[3], L0[4], L0[5], L0[6], L0[7],
                                                MwT0, MuT0, bias0);
  pack_weights_kernel<<<1024, 256, 0, stream>>>(L1[0], L1[1], L1[2], L1[3], L1[4], L1[5], L1[6], L1[7],
                                                MwT1, MuT1, bias1);
  pack_x_kernel<<<16384, 256, 0, stream>>>(x, Apk);
  // layer 0
  gemm_split_kernel<<<dim3(256, 4), 256, 0, stream>>>(Apk, MwT0, bias0, wx);
  scan_kernel<<<8, 256, 0, stream>>>(MuT0, wx, nullptr, Apk, xb0, &cnts[0]);
  // layer 1
  gemm_split_kernel<<<dim3(256, 4), 256, 0, stream>>>(Apk, MwT1, bias1, wx);
  scan_kernel<<<8, 256, 0, stream>>>(MuT1, wx, (float*)d_out, nullptr, xb1, &cnts[8]);
}

// Round 2
// 25986.047 us; speedup vs baseline: 1.6277x; 1.6277x over previous
//
#include <hip/hip_runtime.h>

typedef unsigned int uint;
typedef unsigned long long u64;
typedef __attribute__((ext_vector_type(4))) float f32x4;
typedef __attribute__((ext_vector_type(8))) short s16x8;   // 8 bf16 in 4 VGPRs

union U4 { uint u[4]; s16x8 v; uint4 q; };

#define TT 4096
#define HC2 512

// ---------- helpers ----------
__device__ __forceinline__ uint bf16_rne(float f) {
  uint x = __float_as_uint(f);
  x += 0x7fffu + ((x >> 16) & 1u);
  return x >> 16;
}
// split f into hi(bf16, low 16 bits) + lo(bf16 of remainder, high 16 bits)
__device__ __forceinline__ uint pack_split(float f) {
  uint hi = bf16_rne(f);
  float fh = __uint_as_float(hi << 16);
  uint lo = bf16_rne(f - fh);
  return hi | (lo << 16);
}
__device__ __forceinline__ float fast_tanh(float y) {
  float e = __builtin_amdgcn_exp2f(y * 2.885390081777927f);
  return 1.0f - 2.0f * __builtin_amdgcn_rcpf(e + 1.0f);
}

// system-scope (sc0 sc1) ops: go straight to the coherent point (Infinity Cache),
// never allocate/dirty per-XCD L2 -> no buffer_inv / buffer_wbl2 needed for sync.
__device__ __forceinline__ void st_sys(uint* p, uint v) {
  asm volatile("global_store_dword %0, %1, off sc0 sc1" :: "v"(p), "v"(v) : "memory");
}
__device__ __forceinline__ void drain_vm() {
  asm volatile("s_waitcnt vmcnt(0)" ::: "memory");
}

// ---------- pack weights: M[k][j] stored transposed+split as MT[j][k] (uint32) ----------
__global__ void pack_weights_kernel(const float* __restrict__ wr, const float* __restrict__ wi,
                                    const float* __restrict__ wbr, const float* __restrict__ wbi,
                                    const float* __restrict__ ur, const float* __restrict__ ui,
                                    const float* __restrict__ ubr, const float* __restrict__ ubi,
                                    uint* __restrict__ MwT, uint* __restrict__ MuT,
                                    float* __restrict__ bias) {
  const int id = blockIdx.x * 256 + threadIdx.x;   // 0..262143
  const int j = id >> 9, k = id & 511;
  const int jj = j & 255, kk = k & 255;
  float mw, mu;
  if (k < 256) {
    if (j < 256) { mw =  wr[kk * 256 + jj]; mu =  ur[kk * 256 + jj]; }
    else         { mw =  wi[kk * 256 + jj]; mu =  ui[kk * 256 + jj]; }
  } else {
    if (j < 256) { mw = -wi[kk * 256 + jj]; mu = -ui[kk * 256 + jj]; }
    else         { mw =  wr[kk * 256 + jj]; mu =  ur[kk * 256 + jj]; }
  }
  MwT[id] = pack_split(mw);
  MuT[id] = pack_split(mu);
  if (id < 512)
    bias[id] = (id < 256) ? (wbr[id] + ubr[id]) : (wbi[id - 256] + ubi[id - 256]);
}

// ---------- pack x (fp32 -> split uint32) ----------
__global__ void pack_x_kernel(const float* __restrict__ x, uint* __restrict__ xp) {
  const u64 i = ((u64)blockIdx.x * 256 + threadIdx.x) * 4;
  float4 v = *(const float4*)(x + i);
  uint4 o;
  o.x = pack_split(v.x); o.y = pack_split(v.y);
  o.z = pack_split(v.z); o.w = pack_split(v.w);
  *(uint4*)(xp + i) = o;
}

// ---------- split-bf16 MFMA GEMM:  C[32768][512] = A[32768][512] * B[512][512] + bias ----------
__global__ __launch_bounds__(256, 2)
void gemm_split_kernel(const uint* __restrict__ A, const uint* __restrict__ BT,
                       const float* __restrict__ bias, float* __restrict__ C) {
  __shared__ __align__(16) uint a_s[128][36];
  __shared__ __align__(16) uint b_s[128][36];
  const int tid = threadIdx.x;
  const int wv = tid >> 6, lane = tid & 63;
  const int q = lane >> 4, cl = lane & 15;
  const int row0 = (int)blockIdx.x * 128, col0 = (int)blockIdx.y * 128;
  const int wro = (wv >> 1) * 64, wco = (wv & 1) * 64;
  const int sr = tid >> 1, sc = (tid & 1) * 16;

  f32x4 acc[4][4];
#pragma unroll
  for (int a = 0; a < 4; ++a)
#pragma unroll
    for (int b = 0; b < 4; ++b) acc[a][b] = (f32x4){0.f, 0.f, 0.f, 0.f};

  const uint* ga = A + (u64)(row0 + sr) * 512 + sc;
  const uint* gb = BT + (u64)(col0 + sr) * 512 + sc;

  for (int kb = 0; kb < 16; ++kb) {
    uint4 va0 = *(const uint4*)(ga + 0), va1 = *(const uint4*)(ga + 4);
    uint4 va2 = *(const uint4*)(ga + 8), va3 = *(const uint4*)(ga + 12);
    uint4 vb0 = *(const uint4*)(gb + 0), vb1 = *(const uint4*)(gb + 4);
    uint4 vb2 = *(const uint4*)(gb + 8), vb3 = *(const uint4*)(gb + 12);
    ga += 32; gb += 32;
    __syncthreads();
    *(uint4*)&a_s[sr][sc + 0] = va0;  *(uint4*)&a_s[sr][sc + 4] = va1;
    *(uint4*)&a_s[sr][sc + 8] = va2;  *(uint4*)&a_s[sr][sc + 12] = va3;
    *(uint4*)&b_s[sr][sc + 0] = vb0;  *(uint4*)&b_s[sr][sc + 4] = vb1;
    *(uint4*)&b_s[sr][sc + 8] = vb2;  *(uint4*)&b_s[sr][sc + 12] = vb3;
    __syncthreads();

    s16x8 ah[4], al[4];
#pragma unroll
    for (int rt = 0; rt < 4; ++rt) {
      const uint* p = &a_s[wro + rt * 16 + cl][q * 8];
      uint4 p0 = *(const uint4*)(p), p1 = *(const uint4*)(p + 4);
      U4 th, tl;
      th.u[0] = (p0.x & 0xffffu) | (p0.y << 16);
      th.u[1] = (p0.z & 0xffffu) | (p0.w << 16);
      th.u[2] = (p1.x & 0xffffu) | (p1.y << 16);
      th.u[3] = (p1.z & 0xffffu) | (p1.w << 16);
      tl.u[0] = (p0.x >> 16) | (p0.y & 0xffff0000u);
      tl.u[1] = (p0.z >> 16) | (p0.w & 0xffff0000u);
      tl.u[2] = (p1.x >> 16) | (p1.y & 0xffff0000u);
      tl.u[3] = (p1.z >> 16) | (p1.w & 0xffff0000u);
      ah[rt] = th.v; al[rt] = tl.v;
    }
#pragma unroll
    for (int ct = 0; ct < 4; ++ct) {
      const uint* p = &b_s[wco + ct * 16 + cl][q * 8];
      uint4 p0 = *(const uint4*)(p), p1 = *(const uint4*)(p + 4);
      U4 th, tl;
      th.u[0] = (p0.x & 0xffffu) | (p0.y << 16);
      th.u[1] = (p0.z & 0xffffu) | (p0.w << 16);
      th.u[2] = (p1.x & 0xffffu) | (p1.y << 16);
      th.u[3] = (p1.z & 0xffffu) | (p1.w << 16);
      tl.u[0] = (p0.x >> 16) | (p0.y & 0xffff0000u);
      tl.u[1] = (p0.z >> 16) | (p0.w & 0xffff0000u);
      tl.u[2] = (p1.x >> 16) | (p1.y & 0xffff0000u);
      tl.u[3] = (p1.z >> 16) | (p1.w & 0xffff0000u);
#pragma unroll
      for (int rt = 0; rt < 4; ++rt) {
        acc[rt][ct] = __builtin_amdgcn_mfma_f32_16x16x32_bf16(ah[rt], th.v, acc[rt][ct], 0, 0, 0);
        acc[rt][ct] = __builtin_amdgcn_mfma_f32_16x16x32_bf16(al[rt], th.v, acc[rt][ct], 0, 0, 0);
        acc[rt][ct] = __builtin_amdgcn_mfma_f32_16x16x32_bf16(ah[rt], tl.v, acc[rt][ct], 0, 0, 0);
      }
    }
  }
#pragma unroll
  for (int ct = 0; ct < 4; ++ct) {
    const int col = col0 + wco + ct * 16 + cl;
    const float bv = bias[col];
#pragma unroll
    for (int rt = 0; rt < 4; ++rt) {
      const int rbase = row0 + wro + rt * 16 + q * 4;
#pragma unroll
      for (int r2 = 0; r2 < 4; ++r2)
        C[(u64)(rbase + r2) * 512 + col] = acc[rt][ct][r2] + bv;
    }
  }
}

// ---------- persistent scan: 8 blocks, block w owns output cols [64w,64w+64) ----------
// Full-depth packed exchange buffer xpk[b][t][j]; per-(step,block) flag line; all
// exchange traffic is system-scope (sc0 sc1) -> no L2 inv/wb in the sync path.
__global__ __launch_bounds__(256, 1)
void scan_kernel(const uint* __restrict__ MuT, const float* __restrict__ wxb,
                 float* __restrict__ hout, uint* __restrict__ xpk,
                 uint* __restrict__ flags) {
  __shared__ __align__(16) unsigned short xah[16][520];  // hi plane, rows 8..15 stay zero
  __shared__ __align__(16) unsigned short xal[16][520];  // lo plane
  const int tid = threadIdx.x;
  const int wv = tid >> 6, lane = tid & 63;
  const int q = lane >> 4, cl = lane & 15;
  const int j = (int)blockIdx.x * 64 + wv * 16 + cl;     // this lane's output column

  for (int idx = tid; idx < 16 * 520; idx += 256) {
    ((unsigned short*)xah)[idx] = 0;
    ((unsigned short*)xal)[idx] = 0;
  }

  // recurrent weights -> registers (B-operand frags: col=lane&15, k=q*8+e)
  uint bh[64], bl[64];
  {
    const uint* wrow = MuT + (u64)j * 512;
#pragma unroll
    for (int ks = 0; ks < 16; ++ks) {
      const int k0 = ks * 32 + q * 8;
      uint4 p0 = *(const uint4*)(wrow + k0);
      uint4 p1 = *(const uint4*)(wrow + k0 + 4);
      bh[ks * 4 + 0] = (p0.x & 0xffffu) | (p0.y << 16);
      bh[ks * 4 + 1] = (p0.z & 0xffffu) | (p0.w << 16);
      bh[ks * 4 + 2] = (p1.x & 0xffffu) | (p1.y << 16);
      bh[ks * 4 + 3] = (p1.z & 0xffffu) | (p1.w << 16);
      bl[ks * 4 + 0] = (p0.x >> 16) | (p0.y & 0xffff0000u);
      bl[ks * 4 + 1] = (p0.z >> 16) | (p0.w & 0xffff0000u);
      bl[ks * 4 + 2] = (p1.x >> 16) | (p1.y & 0xffff0000u);
      bl[ks * 4 + 3] = (p1.z >> 16) | (p1.w & 0xffff0000u);
    }
  }
  __syncthreads();

  const int srow = tid >> 5;            // staging: 32 threads per batch row
  const int scol = (tid & 31) * 16;
  const uint* hsrc_base = xpk + (u64)srow * TT * HC2 + scol;

#pragma unroll 1
  for (int t = 0; t < TT; ++t) {
    // prefetch wxb[t] (independent of h) so its latency hides under the poll
    float wpre[4] = {0.f, 0.f, 0.f, 0.f};
    if (q < 2) {
#pragma unroll
      for (int r = 0; r < 4; ++r)
        wpre[r] = wxb[((u64)(q * 4 + r) * TT + t) * HC2 + j];
    }

    f32x4 acc0 = {0.f, 0.f, 0.f, 0.f}, acc1 = acc0, acc2 = acc0;
    if (t > 0) {
      if (tid == 0) {                    // wait for all 8 producer slices of h(t-1)
        const uint* f = flags + (u64)(t - 1) * 8;
        const uint tok = (uint)t;
        uint4 a, b;
        do {
          asm volatile("global_load_dwordx4 %0, %2, off sc0 sc1\n\t"
                       "global_load_dwordx4 %1, %2, off offset:16 sc0 sc1\n\t"
                       "s_waitcnt vmcnt(0)"
                       : "=&v"(a), "=&v"(b)
                       : "v"(f)
                       : "memory");
        } while (a.x != tok || a.y != tok || a.z != tok || a.w != tok ||
                 b.x != tok || b.y != tok || b.z != tok || b.w != tok);
      }
      __syncthreads();
      { // load h(t-1): 64B/thread, coalesced, straight from coherent point
        const uint* src = hsrc_base + (u64)(t - 1) * HC2;
        uint4 p0, p1, p2, p3;
        asm volatile("global_load_dwordx4 %0, %4, off sc0 sc1\n\t"
                     "global_load_dwordx4 %1, %4, off offset:16 sc0 sc1\n\t"
                     "global_load_dwordx4 %2, %4, off offset:32 sc0 sc1\n\t"
                     "global_load_dwordx4 %3, %4, off offset:48 sc0 sc1\n\t"
                     "s_waitcnt vmcnt(0)"
                     : "=&v"(p0), "=&v"(p1), "=&v"(p2), "=&v"(p3)
                     : "v"(src)
                     : "memory");
        uint pcs[16] = {p0.x, p0.y, p0.z, p0.w, p1.x, p1.y, p1.z, p1.w,
                        p2.x, p2.y, p2.z, p2.w, p3.x, p3.y, p3.z, p3.w};
        U4 h0, h1, l0, l1;
#pragma unroll
        for (int e = 0; e < 4; ++e) {
          h0.u[e] = (pcs[2 * e] & 0xffffu) | (pcs[2 * e + 1] << 16);
          l0.u[e] = (pcs[2 * e] >> 16) | (pcs[2 * e + 1] & 0xffff0000u);
          h1.u[e] = (pcs[8 + 2 * e] & 0xffffu) | (pcs[8 + 2 * e + 1] << 16);
          l1.u[e] = (pcs[8 + 2 * e] >> 16) | (pcs[8 + 2 * e + 1] & 0xffff0000u);
        }
        *(uint4*)&xah[srow][scol] = h0.q;  *(uint4*)&xah[srow][scol + 8] = h1.q;
        *(uint4*)&xal[srow][scol] = l0.q;  *(uint4*)&xal[srow][scol + 8] = l1.q;
      }
      __syncthreads();
      // U*h : A frag row=lane&15 (batch), k=q*8+e
#pragma unroll
      for (int ks = 0; ks < 16; ++ks) {
        const int k0 = ks * 32 + q * 8;
        s16x8 ah = *(const s16x8*)&xah[cl][k0];
        s16x8 al = *(const s16x8*)&xal[cl][k0];
        U4 tb, tc;
        tb.u[0] = bh[ks * 4 + 0]; tb.u[1] = bh[ks * 4 + 1];
        tb.u[2] = bh[ks * 4 + 2]; tb.u[3] = bh[ks * 4 + 3];
        tc.u[0] = bl[ks * 4 + 0]; tc.u[1] = bl[ks * 4 + 1];
        tc.u[2] = bl[ks * 4 + 2]; tc.u[3] = bl[ks * 4 + 3];
        acc0 = __builtin_amdgcn_mfma_f32_16x16x32_bf16(ah, tb.v, acc0, 0, 0, 0);
        acc1 = __builtin_amdgcn_mfma_f32_16x16x32_bf16(al, tb.v, acc1, 0, 0, 0);
        acc2 = __builtin_amdgcn_mfma_f32_16x16x32_bf16(ah, tc.v, acc2, 0, 0, 0);
      }
    }
    // epilogue: D row=q*4+r (batch, valid q<2), col=cl
    if (q < 2) {
#pragma unroll
      for (int r = 0; r < 4; ++r) {
        const int b = q * 4 + r;
        const u64 off = ((u64)b * TT + t) * HC2 + j;
        float y = acc0[r] + acc1[r] + acc2[r] + wpre[r];
        float h = fast_tanh(y);
        if (hout) hout[off] = h;
        st_sys(xpk + off, pack_split(h));
      }
    }
    if (t < TT - 1) {
      drain_vm();          // my wave's h stores acked at coherent point
      __syncthreads();     // -> all waves' stores acked
      if (tid == 0) {
        uint tok = (uint)(t + 1);
        st_sys(flags + (u64)t * 8 + blockIdx.x, tok);
      }
    }
  }
}

// ---------- host ----------
extern "C" void kernel_launch(void* const* d_in, const int* in_sizes, int n_in,
                              void* d_out, int out_size, void* d_ws, size_t ws_size,
                              hipStream_t stream) {
  const float* x = (const float*)d_in[0];
  const float* L0[8]; const float* L1[8];
  for (int i = 0; i < 8; ++i) { L0[i] = (const float*)d_in[1 + i]; L1[i] = (const float*)d_in[9 + i]; }

  char* ws = (char*)d_ws;
  const size_t MB = 1024 * 1024;
  uint* MwT0 = (uint*)(ws + 0 * MB);
  uint* MuT0 = (uint*)(ws + 1 * MB);
  uint* MwT1 = (uint*)(ws + 2 * MB);
  uint* MuT1 = (uint*)(ws + 3 * MB);
  float* bias0 = (float*)(ws + 4 * MB);
  float* bias1 = (float*)(ws + 4 * MB + 8192);
  uint* fl0 = (uint*)(ws + 4 * MB + 65536);        // 4096*8*4 = 128 KB
  uint* fl1 = (uint*)(ws + 4 * MB + 65536 + 131072);
  uint* Apk = (uint*)(ws + 8 * MB);      // 64 MB: packed x -> packed h (both scans' exchange)
  float* wx = (float*)(ws + 72 * MB);    // 64 MB: projection output (both layers)

  hipMemsetAsync(ws + 4 * MB + 65536, 0, 262144, stream);  // zero both flag arrays
  pack_weights_kernel<<<1024, 256, 0, stream>>>(L0[0], L0[1], L0[2], L0[3], L0[4], L0[5], L0[6], L0[7],
                                                MwT0, MuT0, bias0);
  pack_weights_kernel<<<1024, 256, 0, stream>>>(L1[0], L1[1], L1[2], L1[3], L1[4], L1[5], L1[6], L1[7],
                                                MwT1, MuT1, bias1);
  pack_x_kernel<<<16384, 256, 0, stream>>>(x, Apk);
  // layer 0
  gemm_split_kernel<<<dim3(256, 4), 256, 0, stream>>>(Apk, MwT0, bias0, wx);
  scan_kernel<<<8, 256, 0, stream>>>(MuT0, wx, nullptr, Apk, fl0);
  // layer 1 (scan reuses Apk as exchange scratch after gemm consumed it)
  gemm_split_kernel<<<dim3(256, 4), 256, 0, stream>>>(Apk, MwT1, bias1, wx);
  scan_kernel<<<8, 256, 0, stream>>>(MuT1, wx, (float*)d_out, Apk, fl1);
}

// Round 4
// 23227.760 us; speedup vs baseline: 1.8209x; 1.1187x over previous
//
#include <hip/hip_runtime.h>

typedef unsigned int uint;
typedef unsigned long long u64;
typedef __attribute__((ext_vector_type(4))) float f32x4;
typedef __attribute__((ext_vector_type(8))) short s16x8;   // 8 bf16 in 4 VGPRs

union U4 { uint u[4]; s16x8 v; uint4 q; };

#define TT 4096
#define HC2 512
#define SENT 0xFFFFFFFFu

// ---------- helpers ----------
__device__ __forceinline__ uint bf16_rne(float f) {
  uint x = __float_as_uint(f);
  x += 0x7fffu + ((x >> 16) & 1u);
  return x >> 16;
}
// split f into hi(bf16, low 16 bits) + lo(bf16 of remainder, high 16 bits)
// NOTE: hi is bf16 of a finite tanh/input value -> never 0xFFFF (NaN pattern),
// so a packed word can never equal SENT. This is the poll sentinel's safety.
__device__ __forceinline__ uint pack_split(float f) {
  uint hi = bf16_rne(f);
  float fh = __uint_as_float(hi << 16);
  uint lo = bf16_rne(f - fh);
  return hi | (lo << 16);
}
__device__ __forceinline__ float fast_tanh(float y) {
  float e = __builtin_amdgcn_exp2f(y * 2.885390081777927f);
  return 1.0f - 2.0f * __builtin_amdgcn_rcpf(e + 1.0f);
}

// system-scope (sc0 sc1): straight to the die-level coherent point (L3);
// never dirties per-XCD L2. The ONLY empirically-validated intra-kernel
// cross-CU path on this part (R2 passed; R3's plain/sc0 within-XCD failed).
__device__ __forceinline__ void st_sys(uint* p, uint v) {
  asm volatile("global_store_dword %0, %1, off sc0 sc1" :: "v"(p), "v"(v) : "memory");
}

// ---------- pack weights: M[k][j] stored transposed+split as MT[j][k] (uint32) ----------
__global__ void pack_weights_kernel(const float* __restrict__ wr, const float* __restrict__ wi,
                                    const float* __restrict__ wbr, const float* __restrict__ wbi,
                                    const float* __restrict__ ur, const float* __restrict__ ui,
                                    const float* __restrict__ ubr, const float* __restrict__ ubi,
                                    uint* __restrict__ MwT, uint* __restrict__ MuT,
                                    float* __restrict__ bias) {
  const int id = blockIdx.x * 256 + threadIdx.x;   // 0..262143
  const int j = id >> 9, k = id & 511;
  const int jj = j & 255, kk = k & 255;
  float mw, mu;
  if (k < 256) {
    if (j < 256) { mw =  wr[kk * 256 + jj]; mu =  ur[kk * 256 + jj]; }
    else         { mw =  wi[kk * 256 + jj]; mu =  ui[kk * 256 + jj]; }
  } else {
    if (j < 256) { mw = -wi[kk * 256 + jj]; mu = -ui[kk * 256 + jj]; }
    else         { mw =  wr[kk * 256 + jj]; mu =  ur[kk * 256 + jj]; }
  }
  MwT[id] = pack_split(mw);
  MuT[id] = pack_split(mu);
  if (id < 512)
    bias[id] = (id < 256) ? (wbr[id] + ubr[id]) : (wbi[id - 256] + ubi[id - 256]);
}

// ---------- pack x (fp32 -> split uint32) ----------
__global__ void pack_x_kernel(const float* __restrict__ x, uint* __restrict__ xp) {
  const u64 i = ((u64)blockIdx.x * 256 + threadIdx.x) * 4;
  float4 v = *(const float4*)(x + i);
  uint4 o;
  o.x = pack_split(v.x); o.y = pack_split(v.y);
  o.z = pack_split(v.z); o.w = pack_split(v.w);
  *(uint4*)(xp + i) = o;
}

// ---------- split-bf16 MFMA GEMM:  C[32768][512] = A[32768][512] * B[512][512] + bias ----------
__global__ __launch_bounds__(256, 2)
void gemm_split_kernel(const uint* __restrict__ A, const uint* __restrict__ BT,
                       const float* __restrict__ bias, float* __restrict__ C) {
  __shared__ __align__(16) uint a_s[128][36];
  __shared__ __align__(16) uint b_s[128][36];
  const int tid = threadIdx.x;
  const int wv = tid >> 6, lane = tid & 63;
  const int q = lane >> 4, cl = lane & 15;
  const int row0 = (int)blockIdx.x * 128, col0 = (int)blockIdx.y * 128;
  const int wro = (wv >> 1) * 64, wco = (wv & 1) * 64;
  const int sr = tid >> 1, sc = (tid & 1) * 16;

  f32x4 acc[4][4];
#pragma unroll
  for (int a = 0; a < 4; ++a)
#pragma unroll
    for (int b = 0; b < 4; ++b) acc[a][b] = (f32x4){0.f, 0.f, 0.f, 0.f};

  const uint* ga = A + (u64)(row0 + sr) * 512 + sc;
  const uint* gb = BT + (u64)(col0 + sr) * 512 + sc;

  for (int kb = 0; kb < 16; ++kb) {
    uint4 va0 = *(const uint4*)(ga + 0), va1 = *(const uint4*)(ga + 4);
    uint4 va2 = *(const uint4*)(ga + 8), va3 = *(const uint4*)(ga + 12);
    uint4 vb0 = *(const uint4*)(gb + 0), vb1 = *(const uint4*)(gb + 4);
    uint4 vb2 = *(const uint4*)(gb + 8), vb3 = *(const uint4*)(gb + 12);
    ga += 32; gb += 32;
    __syncthreads();
    *(uint4*)&a_s[sr][sc + 0] = va0;  *(uint4*)&a_s[sr][sc + 4] = va1;
    *(uint4*)&a_s[sr][sc + 8] = va2;  *(uint4*)&a_s[sr][sc + 12] = va3;
    *(uint4*)&b_s[sr][sc + 0] = vb0;  *(uint4*)&b_s[sr][sc + 4] = vb1;
    *(uint4*)&b_s[sr][sc + 8] = vb2;  *(uint4*)&b_s[sr][sc + 12] = vb3;
    __syncthreads();

    s16x8 ah[4], al[4];
#pragma unroll
    for (int rt = 0; rt < 4; ++rt) {
      const uint* p = &a_s[wro + rt * 16 + cl][q * 8];
      uint4 p0 = *(const uint4*)(p), p1 = *(const uint4*)(p + 4);
      U4 th, tl;
      th.u[0] = (p0.x & 0xffffu) | (p0.y << 16);
      th.u[1] = (p0.z & 0xffffu) | (p0.w << 16);
      th.u[2] = (p1.x & 0xffffu) | (p1.y << 16);
      th.u[3] = (p1.z & 0xffffu) | (p1.w << 16);
      tl.u[0] = (p0.x >> 16) | (p0.y & 0xffff0000u);
      tl.u[1] = (p0.z >> 16) | (p0.w & 0xffff0000u);
      tl.u[2] = (p1.x >> 16) | (p1.y & 0xffff0000u);
      tl.u[3] = (p1.z >> 16) | (p1.w & 0xffff0000u);
      ah[rt] = th.v; al[rt] = tl.v;
    }
#pragma unroll
    for (int ct = 0; ct < 4; ++ct) {
      const uint* p = &b_s[wco + ct * 16 + cl][q * 8];
      uint4 p0 = *(const uint4*)(p), p1 = *(const uint4*)(p + 4);
      U4 th, tl;
      th.u[0] = (p0.x & 0xffffu) | (p0.y << 16);
      th.u[1] = (p0.z & 0xffffu) | (p0.w << 16);
      th.u[2] = (p1.x & 0xffffu) | (p1.y << 16);
      th.u[3] = (p1.z & 0xffffu) | (p1.w << 16);
      tl.u[0] = (p0.x >> 16) | (p0.y & 0xffff0000u);
      tl.u[1] = (p0.z >> 16) | (p0.w & 0xffff0000u);
      tl.u[2] = (p1.x >> 16) | (p1.y & 0xffff0000u);
      tl.u[3] = (p1.z >> 16) | (p1.w & 0xffff0000u);
#pragma unroll
      for (int rt = 0; rt < 4; ++rt) {
        acc[rt][ct] = __builtin_amdgcn_mfma_f32_16x16x32_bf16(ah[rt], th.v, acc[rt][ct], 0, 0, 0);
        acc[rt][ct] = __builtin_amdgcn_mfma_f32_16x16x32_bf16(al[rt], th.v, acc[rt][ct], 0, 0, 0);
        acc[rt][ct] = __builtin_amdgcn_mfma_f32_16x16x32_bf16(ah[rt], tl.v, acc[rt][ct], 0, 0, 0);
      }
    }
  }
#pragma unroll
  for (int ct = 0; ct < 4; ++ct) {
    const int col = col0 + wco + ct * 16 + cl;
    const float bv = bias[col];
#pragma unroll
    for (int rt = 0; rt < 4; ++rt) {
      const int rbase = row0 + wro + rt * 16 + q * 4;
#pragma unroll
      for (int r2 = 0; r2 < 4; ++r2)
        C[(u64)(rbase + r2) * 512 + col] = acc[rt][ct][r2] + bv;
    }
  }
}

// ---------- persistent scan: 8 blocks; block s owns cols [64s,64s+64) ----------
// NO flags: consumers poll the h-data itself (exchange buffer pre-memset to
// SENT; packed h words can never equal SENT). All exchange ops sc0 sc1 (L3).
// One barrier/step. LDS WAR safety: a wave stages h(t) only after observing
// every producer wave's h(t) words, and each producer's h(t) stores
// data-depend on its own step-t ds_reads.
__global__ __launch_bounds__(256, 1)
void scan_kernel(const uint* __restrict__ MuT, const float* __restrict__ wxb,
                 float* __restrict__ hout, uint* __restrict__ xpk) {
  __shared__ __align__(16) unsigned short xah[16][520];  // hi plane, rows 8..15 stay zero
  __shared__ __align__(16) unsigned short xal[16][520];  // lo plane
  const int tid = threadIdx.x;
  const int wv = tid >> 6, lane = tid & 63;
  const int q = lane >> 4, cl = lane & 15;
  const int j = (int)blockIdx.x * 64 + wv * 16 + cl;     // this lane's output column

  for (int idx = tid; idx < 16 * 520; idx += 256) {
    ((unsigned short*)xah)[idx] = 0;
    ((unsigned short*)xal)[idx] = 0;
  }

  // recurrent weights -> registers (B-operand frags: col=lane&15, k=q*8+e)
  uint4 bh4[16], bl4[16];
  {
    const uint* wrow = MuT + (u64)j * 512;
#pragma unroll
    for (int ks = 0; ks < 16; ++ks) {
      const int k0 = ks * 32 + q * 8;
      uint4 p0 = *(const uint4*)(wrow + k0);
      uint4 p1 = *(const uint4*)(wrow + k0 + 4);
      uint4 h, l;
      h.x = (p0.x & 0xffffu) | (p0.y << 16);
      h.y = (p0.z & 0xffffu) | (p0.w << 16);
      h.z = (p1.x & 0xffffu) | (p1.y << 16);
      h.w = (p1.z & 0xffffu) | (p1.w << 16);
      l.x = (p0.x >> 16) | (p0.y & 0xffff0000u);
      l.y = (p0.z >> 16) | (p0.w & 0xffff0000u);
      l.z = (p1.x >> 16) | (p1.y & 0xffff0000u);
      l.w = (p1.z >> 16) | (p1.w & 0xffff0000u);
      bh4[ks] = h; bl4[ks] = l;
    }
  }
  __syncthreads();

  const int srow = tid >> 5;            // staging: 32 threads per batch row
  const int scol = (tid & 31) * 16;
  const uint* hsrc_base = xpk + (u64)srow * TT * HC2 + scol;
  bool timeout = false;

#pragma unroll 1
  for (int t = 0; t < TT; ++t) {
    // prefetch wxb[t] (independent of h) so its latency hides under the poll
    float wpre[4] = {0.f, 0.f, 0.f, 0.f};
    if (q < 2) {
#pragma unroll
      for (int r = 0; r < 4; ++r)
        wpre[r] = wxb[((u64)(q * 4 + r) * TT + t) * HC2 + j];
    }

    f32x4 acc0 = {0.f, 0.f, 0.f, 0.f}, acc1 = acc0, acc2 = acc0;
    if (t > 0) {
      // poll h(t-1) data at L3 until this wave's full row-set is non-sentinel
      const uint* src = hsrc_base + (u64)(t - 1) * HC2;
      uint4 p0, p1, p2, p3;
      int spin = 0;
      for (;;) {
        asm volatile("global_load_dwordx4 %0, %4, off sc0 sc1\n\t"
                     "global_load_dwordx4 %1, %4, off offset:16 sc0 sc1\n\t"
                     "global_load_dwordx4 %2, %4, off offset:32 sc0 sc1\n\t"
                     "global_load_dwordx4 %3, %4, off offset:48 sc0 sc1\n\t"
                     "s_waitcnt vmcnt(0)"
                     : "=&v"(p0), "=&v"(p1), "=&v"(p2), "=&v"(p3)
                     : "v"(src)
                     : "memory");
        bool ok = timeout ||
                  (p0.x != SENT && p0.y != SENT && p0.z != SENT && p0.w != SENT &&
                   p1.x != SENT && p1.y != SENT && p1.z != SENT && p1.w != SENT &&
                   p2.x != SENT && p2.y != SENT && p2.z != SENT && p2.w != SENT &&
                   p3.x != SENT && p3.y != SENT && p3.z != SENT && p3.w != SENT);
        if (__ballot(ok) == ~0ull) break;
        if (++spin > (1 << 20)) { timeout = true; break; }   // fail fast, never hang
      }
      { // stage into LDS hi/lo planes
        uint pcs[16] = {p0.x, p0.y, p0.z, p0.w, p1.x, p1.y, p1.z, p1.w,
                        p2.x, p2.y, p2.z, p2.w, p3.x, p3.y, p3.z, p3.w};
        U4 h0, h1, l0, l1;
#pragma unroll
        for (int e = 0; e < 4; ++e) {
          h0.u[e] = (pcs[2 * e] & 0xffffu) | (pcs[2 * e + 1] << 16);
          l0.u[e] = (pcs[2 * e] >> 16) | (pcs[2 * e + 1] & 0xffff0000u);
          h1.u[e] = (pcs[8 + 2 * e] & 0xffffu) | (pcs[8 + 2 * e + 1] << 16);
          l1.u[e] = (pcs[8 + 2 * e] >> 16) | (pcs[8 + 2 * e + 1] & 0xffff0000u);
        }
        *(uint4*)&xah[srow][scol] = h0.q;  *(uint4*)&xah[srow][scol + 8] = h1.q;
        *(uint4*)&xal[srow][scol] = l0.q;  *(uint4*)&xal[srow][scol + 8] = l1.q;
      }
      __syncthreads();                  // the single per-step barrier
      // U*h : A frag row=lane&15 (batch), k=q*8+e
#pragma unroll
      for (int ks = 0; ks < 16; ++ks) {
        const int k0 = ks * 32 + q * 8;
        s16x8 ah = *(const s16x8*)&xah[cl][k0];
        s16x8 al = *(const s16x8*)&xal[cl][k0];
        U4 tb, tc;
        tb.q = bh4[ks];
        tc.q = bl4[ks];
        acc0 = __builtin_amdgcn_mfma_f32_16x16x32_bf16(ah, tb.v, acc0, 0, 0, 0);
        acc1 = __builtin_amdgcn_mfma_f32_16x16x32_bf16(al, tb.v, acc1, 0, 0, 0);
        acc2 = __builtin_amdgcn_mfma_f32_16x16x32_bf16(ah, tc.v, acc2, 0, 0, 0);
      }
    }
    // epilogue: D row=q*4+r (batch, valid q<2), col=cl
    if (q < 2) {
#pragma unroll
      for (int r = 0; r < 4; ++r) {
        const int b = q * 4 + r;
        const u64 off = ((u64)b * TT + t) * HC2 + j;
        float y = acc0[r] + acc1[r] + acc2[r] + wpre[r];
        float h = fast_tanh(y);
        if (hout) hout[off] = h;
        st_sys(xpk + off, pack_split(h));   // consumers poll this word directly
      }
    }
  }
}

// ---------- host ----------
extern "C" void kernel_launch(void* const* d_in, const int* in_sizes, int n_in,
                              void* d_out, int out_size, void* d_ws, size_t ws_size,
                              hipStream_t stream) {
  const float* x = (const float*)d_in[0];
  const float* L0[8]; const float* L1[8];
  for (int i = 0; i < 8; ++i) { L0[i] = (const float*)d_in[1 + i]; L1[i] = (const float*)d_in[9 + i]; }

  char* ws = (char*)d_ws;
  const size_t MB = 1024 * 1024;
  uint* MwT0 = (uint*)(ws + 0 * MB);
  uint* MuT0 = (uint*)(ws + 1 * MB);
  uint* MwT1 = (uint*)(ws + 2 * MB);
  uint* MuT1 = (uint*)(ws + 3 * MB);
  float* bias0 = (float*)(ws + 4 * MB);
  float* bias1 = (float*)(ws + 4 * MB + 8192);
  uint* Apk = (uint*)(ws + 8 * MB);      // 64 MB: packed x -> packed h (exchange for both scans)
  float* wx = (float*)(ws + 72 * MB);    // 64 MB: projection output (both layers)

  pack_weights_kernel<<<1024, 256, 0, stream>>>(L0[0], L0[1], L0[2], L0[3], L0[4], L0[5], L0[6], L0[7],
                                                MwT0, MuT0, bias0);
  pack_weights_kernel<<<1024, 256, 0, stream>>>(L1[0], L1[1], L1[2], L1[3], L1[4], L1[5], L1[6], L1[7],
                                                MwT1, MuT1, bias1);
  pack_x_kernel<<<16384, 256, 0, stream>>>(x, Apk);
  // layer 0
  gemm_split_kernel<<<dim3(256, 4), 256, 0, stream>>>(Apk, MwT0, bias0, wx);
  hipMemsetAsync(Apk, 0xFF, 64 * MB, stream);           // sentinel-poison exchange buffer
  scan_kernel<<<8, 256, 0, stream>>>(MuT0, wx, nullptr, Apk);
  // layer 1 (gemm consumes Apk = packed h0, then Apk is re-poisoned for scan 2)
  gemm_split_kernel<<<dim3(256, 4), 256, 0, stream>>>(Apk, MwT1, bias1, wx);
  hipMemsetAsync(Apk, 0xFF, 64 * MB, stream);
  scan_kernel<<<8, 256, 0, stream>>>(MuT1, wx, (float*)d_out, Apk);
}